// Round 10
// baseline (1743.044 us; speedup 1.0000x reference)
//
#include <hip/hip_runtime.h>

#define T_STEPS 31
#define CIN     64
#define COUT    512
#define WSLEN   512
#define CSTRIDE 16
#define KRED    2048                 // CIN*32
#define NBATCH  1024
#define BCHUNK  512                  // batch rows per pass (seq buffer reuse)
#define MCHUNK  (BCHUNK * T_STEPS)   // 15872 rows per pass

typedef int v4i __attribute__((ext_vector_type(4)));

__device__ __forceinline__ double clip01d(double v) { return fmin(fmax(v, 0.0), 1.0); }

// ---------------------------------------------------------------------------
// Digitize 4 pre-scaled floats (|v| < 0.75) into 5 base-128 digits each,
// packed one byte per element per plane. Exact extraction (proven R8).
// ---------------------------------------------------------------------------
__device__ __forceinline__ void dig5(float4 f, unsigned int w[5]) {
    float vv[4] = {f.x, f.y, f.z, f.w};
    unsigned int w0 = 0, w1 = 0, w2 = 0, w3 = 0, w4 = 0;
    #pragma unroll
    for (int e = 0; e < 4; ++e) {
        float v  = vv[e];
        float c0 = rintf(v * 16384.0f);                     // d1*128+d2
        float r1 = fmaf(c0, -6.103515625e-05f, v);          // v - c0*2^-14
        float c1 = rintf(r1 * 268435456.0f);                // d3*128+d4
        float r2 = fmaf(c1, -3.725290298461914e-09f, r1);   // r1 - c1*2^-28
        float c2 = rintf(r2 * 34359738368.0f);              // d5 = r2*2^35
        int i0 = (int)c0, i1 = (int)c1, i2 = (int)c2;
        int d2 = ((i0 + 64) & 127) - 64;                    // balanced split
        int d1 = (i0 - d2) >> 7;
        int d4 = ((i1 + 64) & 127) - 64;
        int d3 = (i1 - d4) >> 7;
        w0 |= (unsigned int)(d1 & 255) << (8 * e);
        w1 |= (unsigned int)(d2 & 255) << (8 * e);
        w2 |= (unsigned int)(d3 & 255) << (8 * e);
        w3 |= (unsigned int)(d4 & 255) << (8 * e);
        w4 |= (unsigned int)(i2 & 255) << (8 * e);
    }
    w[0] = w0; w[1] = w1; w[2] = w2; w[3] = w3; w[4] = w4;
}

// ---------------------------------------------------------------------------
// Prep 1: transpose fc1_w [co][c] -> fc1wT [c][co]  (f32, exact)
// ---------------------------------------------------------------------------
__global__ __launch_bounds__(256) void prep_fc1_kernel(
    const float* __restrict__ fc1_w, float* __restrict__ fc1wT)
{
    int idx = blockIdx.x * 256 + threadIdx.x;      // 262144 threads
    int co = idx & 511;
    int r  = idx >> 9;
    fc1wT[idx] = fc1_w[co * COUT + r];
}

// ---------------------------------------------------------------------------
// Prep 2: digitize conv_w (scaled by 4 = 1/s_B) into 5 i8 digit planes in
// mfma_i32_16x16x64_i8 B-fragment order (unchanged from R8).
// ---------------------------------------------------------------------------
__global__ __launch_bounds__(256) void prep_bd_kernel(
    const float* __restrict__ conv_w, signed char* __restrict__ Bd)
{
    int t  = blockIdx.x * 256 + threadIdx.x;       // 262144 threads
    int k4 = (t & 511) << 2;                       // 0..2044
    int co = t >> 9;                               // 0..511
    float4 w4 = *(const float4*)(conv_w + (size_t)co * KRED + k4);
    float4 v4 = make_float4(w4.x * 4.0f, w4.y * 4.0f, w4.z * 4.0f, w4.w * 4.0f);
    unsigned int pk[5];
    dig5(v4, pk);
    int off = (((k4 >> 6) * 32 + (co >> 4)) << 10)
            + ((co & 15) + ((k4 >> 4) & 3) * 16) * 16 + (k4 & 15);
    #pragma unroll
    for (int q = 0; q < 5; ++q)
        *(unsigned int*)(Bd + q * 1048576 + off) = pk[q];
}

// ---------------------------------------------------------------------------
// Conv1d + BN via exact i8-digit MFMA, v4: block = 32 rows x 128 cols.
// Keeps R9's A-amortization (A digitized once per block per kt, shared by
// 8 col-tiles) but restores R8's 2-subtile wave: 8 waves, wave = 16 rows x
// 32 cols, acc[2][5] = 40 accums -> 2 blocks/CU occupancy (R9 failed at 1).
// Per thread per kt: ONE dig5 (4 elements, 4B/plane) + 5x16B B staging.
// ---------------------------------------------------------------------------
__global__ __launch_bounds__(512, 2) void conv_bn_i8v4_kernel(
    const float* __restrict__ x, const signed char* __restrict__ Bd,
    const float* __restrict__ conv_b,
    const float* __restrict__ bn_gamma, const float* __restrict__ bn_beta,
    const float* __restrict__ bn_mean,  const float* __restrict__ bn_var,
    double* __restrict__ seq, int b_base)
{
    __shared__ __align__(16) signed char Alds[5 * 2048];   // plane p: p*2048 + rg*1024
    __shared__ __align__(16) signed char Blds[5 * 8192];   // plane q: q*8192 + ctl*1024

    const int tid = threadIdx.x;
    const int nMB = MCHUNK / 32;           // 496
    const int bm  = blockIdx.x % nMB;
    const int bnk = blockIdx.x / nMB;      // 0..3 (128-col blocks)
    const int m0 = bm * 32, n0 = bnk * 128;

    // --- A digitize/staging map: thread -> (row rA 0..31, k-quad kqA, 4B qtr jq)
    const int rA  = tid & 31;
    const int gA  = tid >> 5;              // 0..15
    const int kqA = gA & 3;
    const int jq  = gA >> 2;               // 0..3
    const int mA  = m0 + rA;
    const int bA  = b_base + mA / T_STEPS;
    const int tA  = mA % T_STEPS;
    const float* xp = x + (size_t)bA * CIN * WSLEN + tA * CSTRIDE;
    const int awb  = ((rA >> 4) << 10) + ((rA & 15) + kqA * 16) * 16 + jq * 4;
    const int kloc = kqA * 16 + jq * 4;    // k offset within the 64-wide tile

    // --- B staging map: per kt, 5 planes x 8KB; thread covers one 16B slot
    //     per plane: col-tile-local ctl = tid>>6, slot sl = tid&63.
    const int ctl = tid >> 6;
    const int sl  = tid & 63;
    const size_t boff0 = (((size_t)(bnk * 8 + ctl)) << 10) + sl * 16;

    // --- MFMA map: wave = 16 rows x 32 cols (2 subtiles) ---
    const int wv  = tid >> 6;
    const int l   = tid & 63;
    const int rgM = wv >> 2;               // row group 0..1
    const int cw  = wv & 3;                // col pair: tiles cw*2 + s

    v4i acc[2][5];                         // [subtile][diagonal]
    #pragma unroll
    for (int s = 0; s < 2; ++s)
        #pragma unroll
        for (int d = 0; d < 5; ++d) acc[s][d] = (v4i){0, 0, 0, 0};

    // ---- prologue: issue tile-0 global loads ----
    uint4 sb[5];
    float4 sxa;
    #pragma unroll
    for (int q = 0; q < 5; ++q)
        sb[q] = *(const uint4*)(Bd + (size_t)q * 1048576 + boff0);
    sxa = *(const float4*)(xp + (kloc >> 5) * WSLEN + (kloc & 31));

    for (int kt = 0; kt < 32; ++kt) {
        // digitize A (s_A = 8): 4 elements -> 4B per plane
        unsigned int pa[5];
        dig5(make_float4(sxa.x * 0.125f, sxa.y * 0.125f, sxa.z * 0.125f, sxa.w * 0.125f), pa);

        __syncthreads();                   // previous fragment reads complete
        #pragma unroll
        for (int p = 0; p < 5; ++p)
            *(unsigned int*)(Alds + p * 2048 + awb) = pa[p];
        #pragma unroll
        for (int q = 0; q < 5; ++q)
            *(uint4*)(Blds + q * 8192 + ctl * 1024 + sl * 16) = sb[q];

        // issue next tile's global loads
        if (kt + 1 < 32) {
            size_t ko = (size_t)(kt + 1) * 32768;
            #pragma unroll
            for (int q = 0; q < 5; ++q)
                sb[q] = *(const uint4*)(Bd + (size_t)q * 1048576 + boff0 + ko);
            int gk = (kt + 1) * 64 + kloc;
            sxa = *(const float4*)(xp + (gk >> 5) * WSLEN + (gk & 31));
        }
        __syncthreads();                   // staged data visible

        v4i aF[5];
        #pragma unroll
        for (int p = 0; p < 5; ++p)
            aF[p] = *(const v4i*)(Alds + p * 2048 + (rgM << 10) + (l << 4));

        #define MF(A_, B_, C_) __builtin_amdgcn_mfma_i32_16x16x64_i8(A_, B_, C_, 0, 0, 0)
        #pragma unroll
        for (int s = 0; s < 2; ++s) {
            const signed char* bb = Blds + ((cw * 2 + s) << 10) + (l << 4);
            v4i b0 = *(const v4i*)(bb);
            v4i b1 = *(const v4i*)(bb + 8192);
            v4i b2 = *(const v4i*)(bb + 16384);
            v4i b3 = *(const v4i*)(bb + 24576);
            v4i b4 = *(const v4i*)(bb + 32768);
            acc[s][0] = MF(aF[0], b0, acc[s][0]);
            acc[s][1] = MF(aF[1], b0, MF(aF[0], b1, acc[s][1]));
            acc[s][2] = MF(aF[2], b0, MF(aF[1], b1, MF(aF[0], b2, acc[s][2])));
            acc[s][3] = MF(aF[3], b0, MF(aF[2], b1, MF(aF[1], b2, MF(aF[0], b3, acc[s][3]))));
            acc[s][4] = MF(aF[4], b0, MF(aF[3], b1, MF(aF[2], b2, MF(aF[1], b3, MF(aF[0], b4, acc[s][4])))));
        }
        #undef MF
    }

    // ---- epilogue: exact f64 reconstruction + conv bias + BN, store f64 ----
    const int l15 = l & 15;
    const int rq  = l >> 4;
    #pragma unroll
    for (int s = 0; s < 2; ++s) {
        const int co = n0 + (cw * 2 + s) * 16 + l15;
        const double g   = (double)bn_gamma[co];
        const double be  = (double)bn_beta[co];
        const double mn  = (double)bn_mean[co];
        const double vr  = (double)bn_var[co];
        const double cb  = (double)conv_b[co];
        const double inv = 1.0 / sqrt(vr + 1e-5);
        #pragma unroll
        for (int r = 0; r < 4; ++r) {
            double v = (double)acc[s][0][r] * 0x1p-13
                     + (double)acc[s][1][r] * 0x1p-20
                     + (double)acc[s][2][r] * 0x1p-27
                     + (double)acc[s][3][r] * 0x1p-34
                     + (double)acc[s][4][r] * 0x1p-41;
            int m = m0 + rgM * 16 + rq * 4 + r;
            seq[(size_t)m * COUT + co] = g * (v + cb - mn) * inv + be;
        }
    }
}

// ---------------------------------------------------------------------------
// SNN scan v3 (unchanged): 1 batch row per block, 512 threads.
// ---------------------------------------------------------------------------
__global__ __launch_bounds__(512, 4) void snn_scan_v3_kernel(
    const double* __restrict__ seq, const float* __restrict__ fc1wT,
    const float* __restrict__ fc1_b, const float* __restrict__ fc2_w,
    const float* __restrict__ fc2_b, const float* __restrict__ beta_enc,
    const float* __restrict__ beta_hid, const float* __restrict__ beta_out,
    float* __restrict__ out, int b_base)
{
    __shared__ int   list[COUT];
    __shared__ int   wcnt[8];
    __shared__ double red[8][2];

    const int tid  = threadIdx.x;
    const int lane = tid & 63;
    const int wave = tid >> 6;
    const int row  = blockIdx.x;
    const int brow = b_base + row;

    const double be  = clip01d((double)beta_enc[tid]);
    const double bh  = clip01d((double)beta_hid[tid]);
    const double f1b = (double)fc1_b[tid];
    const double w2a = (double)fc2_w[tid];
    const double w2b = (double)fc2_w[COUT + tid];

    double bo = 0.0, f2b = 0.0, om = 0.0;
    if (tid < 2) { bo = clip01d((double)beta_out[tid]); f2b = (double)fc2_b[tid]; }

    double em = 0.0, hm = 0.0;
    const double* sp = seq + (size_t)row * T_STEPS * COUT + tid;

    for (int t = 0; t < T_STEPS; ++t) {
        double inp = sp[(size_t)t * COUT];
        double e = be * em + inp - ((em > 1.0) ? 1.0 : 0.0);
        em = e;
        bool spike = (e > 1.0);

        unsigned long long mask = __ballot(spike);
        if (lane == 0) wcnt[wave] = __popcll(mask);
        __syncthreads();

        int base = 0, cnt = 0;
        #pragma unroll
        for (int w = 0; w < 8; ++w) {
            int v = wcnt[w];
            base += (w < wave) ? v : 0;
            cnt  += v;
        }
        if (spike) {
            int pos = base + __popcll(mask & ((1ull << lane) - 1ull));
            list[pos] = tid;
        }
        __syncthreads();

        double s0 = 0.0, s1 = 0.0, s2 = 0.0, s3 = 0.0;
        const float* fw = fc1wT + tid;
        int i = 0;
        for (; i + 4 <= cnt; i += 4) {
            int cA = list[i], cB = list[i + 1], cC = list[i + 2], cD = list[i + 3];
            float wA = fw[(size_t)cA * COUT];
            float wB = fw[(size_t)cB * COUT];
            float wC = fw[(size_t)cC * COUT];
            float wD = fw[(size_t)cD * COUT];
            s0 += (double)wA;
            s1 += (double)wB;
            s2 += (double)wC;
            s3 += (double)wD;
        }
        for (; i < cnt; ++i) s0 += (double)fw[(size_t)list[i] * COUT];
        double cur1 = ((s0 + s1) + (s2 + s3)) + f1b;

        double h = bh * hm + cur1 - ((hm > 1.0) ? 1.0 : 0.0);
        hm = h;
        double sh = (h > 1.0) ? 1.0 : 0.0;
        double p0 = sh * w2a;
        double p1 = sh * w2b;
        #pragma unroll
        for (int off = 32; off > 0; off >>= 1) {
            p0 += __shfl_down(p0, off);
            p1 += __shfl_down(p1, off);
        }
        if (lane == 0) { red[wave][0] = p0; red[wave][1] = p1; }
        __syncthreads();

        if (tid < 2) {
            double cur2 = f2b;
            #pragma unroll
            for (int w = 0; w < 8; ++w) cur2 += red[w][tid];
            double o = bo * om + cur2 - ((om > 1.0) ? 1.0 : 0.0);
            om = o;
            float so = (o > 1.0) ? 1.0f : 0.0f;
            int bidx = brow * 2 + tid;
            out[2048 + t * 2048 + bidx] = so;               // spk_rec
            out[2048 + 63488 + t * 2048 + bidx] = (float)o; // mem_rec
            if (t == T_STEPS - 1) out[bidx] = (float)o;     // final om
        }
    }
}

// ---------------------------------------------------------------------------
extern "C" void kernel_launch(void* const* d_in, const int* in_sizes, int n_in,
                              void* d_out, int out_size, void* d_ws, size_t ws_size,
                              hipStream_t stream)
{
    const float* x        = (const float*)d_in[0];
    const float* conv_w   = (const float*)d_in[1];
    const float* conv_b   = (const float*)d_in[2];
    const float* bn_gamma = (const float*)d_in[3];
    const float* bn_beta  = (const float*)d_in[4];
    const float* bn_mean  = (const float*)d_in[5];
    const float* bn_var   = (const float*)d_in[6];
    const float* fc1_w    = (const float*)d_in[7];
    const float* fc1_b    = (const float*)d_in[8];
    const float* fc2_w    = (const float*)d_in[9];
    const float* fc2_b    = (const float*)d_in[10];
    const float* beta_enc = (const float*)d_in[11];
    const float* beta_hid = (const float*)d_in[12];
    const float* beta_out = (const float*)d_in[13];
    float* out = (float*)d_out;

    // ws layout: Bd 5 MB | fc1wT 1 MB | seq 65 MB  (71.25 MB total)
    signed char* Bd    = (signed char*)d_ws;
    float*       fc1wT = (float*)((char*)d_ws + 5 * 1048576);
    double*      seq   = (double*)((char*)d_ws + 6 * 1048576);

    prep_fc1_kernel<<<1024, 256, 0, stream>>>(fc1_w, fc1wT);
    prep_bd_kernel<<<1024, 256, 0, stream>>>(conv_w, Bd);

    for (int chunk = 0; chunk < 2; ++chunk) {
        int b_base = chunk * BCHUNK;
        conv_bn_i8v4_kernel<<<(MCHUNK / 32) * (COUT / 128), 512, 0, stream>>>(
            x, Bd, conv_b, bn_gamma, bn_beta, bn_mean, bn_var, seq, b_base);
        snn_scan_v3_kernel<<<BCHUNK, 512, 0, stream>>>(
            seq, fc1wT, fc1_b, fc2_w, fc2_b, beta_enc, beta_hid, beta_out, out, b_base);
    }
}

// Round 11
// 881.586 us; speedup vs baseline: 1.9772x; 1.9772x over previous
//
#include <hip/hip_runtime.h>

#define T_STEPS 31
#define CIN     64
#define COUT    512
#define WSLEN   512
#define CSTRIDE 16
#define KRED    2048                 // CIN*32
#define NBATCH  1024
#define BCHUNK  512                  // batch rows per pass (seq buffer reuse)
#define MCHUNK  (BCHUNK * T_STEPS)   // 15872 rows per pass

typedef int v4i __attribute__((ext_vector_type(4)));

__device__ __forceinline__ double clip01d(double v) { return fmin(fmax(v, 0.0), 1.0); }

// ---------------------------------------------------------------------------
// Digitize 4 pre-scaled floats (|v| < 0.75) into 5 base-128 digits each,
// packed one byte per element per plane. Exact extraction (proven R8).
// ---------------------------------------------------------------------------
__device__ __forceinline__ void dig5(float4 f, unsigned int w[5]) {
    float vv[4] = {f.x, f.y, f.z, f.w};
    unsigned int w0 = 0, w1 = 0, w2 = 0, w3 = 0, w4 = 0;
    #pragma unroll
    for (int e = 0; e < 4; ++e) {
        float v  = vv[e];
        float c0 = rintf(v * 16384.0f);                     // d1*128+d2
        float r1 = fmaf(c0, -6.103515625e-05f, v);          // v - c0*2^-14
        float c1 = rintf(r1 * 268435456.0f);                // d3*128+d4
        float r2 = fmaf(c1, -3.725290298461914e-09f, r1);   // r1 - c1*2^-28
        float c2 = rintf(r2 * 34359738368.0f);              // d5 = r2*2^35
        int i0 = (int)c0, i1 = (int)c1, i2 = (int)c2;
        int d2 = ((i0 + 64) & 127) - 64;                    // balanced split
        int d1 = (i0 - d2) >> 7;
        int d4 = ((i1 + 64) & 127) - 64;
        int d3 = (i1 - d4) >> 7;
        w0 |= (unsigned int)(d1 & 255) << (8 * e);
        w1 |= (unsigned int)(d2 & 255) << (8 * e);
        w2 |= (unsigned int)(d3 & 255) << (8 * e);
        w3 |= (unsigned int)(d4 & 255) << (8 * e);
        w4 |= (unsigned int)(i2 & 255) << (8 * e);
    }
    w[0] = w0; w[1] = w1; w[2] = w2; w[3] = w3; w[4] = w4;
}

// ---------------------------------------------------------------------------
// Prep 1: transpose fc1_w [co][c] -> fc1wT [c][co]  (f32, exact)
// ---------------------------------------------------------------------------
__global__ __launch_bounds__(256) void prep_fc1_kernel(
    const float* __restrict__ fc1_w, float* __restrict__ fc1wT)
{
    int idx = blockIdx.x * 256 + threadIdx.x;      // 262144 threads
    int co = idx & 511;
    int r  = idx >> 9;
    fc1wT[idx] = fc1_w[co * COUT + r];
}

// ---------------------------------------------------------------------------
// Prep 2: digitize conv_w (scaled by 4 = 1/s_B) into 5 i8 digit planes in
// mfma_i32_16x16x64_i8 B-fragment order (unchanged from R8).
// ---------------------------------------------------------------------------
__global__ __launch_bounds__(256) void prep_bd_kernel(
    const float* __restrict__ conv_w, signed char* __restrict__ Bd)
{
    int t  = blockIdx.x * 256 + threadIdx.x;       // 262144 threads
    int k4 = (t & 511) << 2;                       // 0..2044
    int co = t >> 9;                               // 0..511
    float4 w4 = *(const float4*)(conv_w + (size_t)co * KRED + k4);
    float4 v4 = make_float4(w4.x * 4.0f, w4.y * 4.0f, w4.z * 4.0f, w4.w * 4.0f);
    unsigned int pk[5];
    dig5(v4, pk);
    int off = (((k4 >> 6) * 32 + (co >> 4)) << 10)
            + ((co & 15) + ((k4 >> 4) & 3) * 16) * 16 + (k4 & 15);
    #pragma unroll
    for (int q = 0; q < 5; ++q)
        *(unsigned int*)(Bd + q * 1048576 + off) = pk[q];
}

// ---------------------------------------------------------------------------
// Conv1d + BN via exact i8-digit MFMA, v5: block = 1024 thr (16 waves),
// 64 rows x 128 cols. Wave = 16 rows x 32 cols = 2 subtiles, acc[2][5]=40
// accums (R8's proven register shape). A digitized ONCE per block per kt
// (one dig5/thread, 4x redundancy vs R8's 8x). Prefetch in NAMED scalars
// (sb0/sb1/sb2 + sxa) -- R10's uint4 sb[5] array was spilled to scratch
// (WRITE_SIZE 63MB -> 1.7GB); arrays are banned here.
// ---------------------------------------------------------------------------
__global__ __launch_bounds__(1024, 4) void conv_bn_i8v5_kernel(
    const float* __restrict__ x, const signed char* __restrict__ Bd,
    const float* __restrict__ conv_b,
    const float* __restrict__ bn_gamma, const float* __restrict__ bn_beta,
    const float* __restrict__ bn_mean,  const float* __restrict__ bn_var,
    double* __restrict__ seq, int b_base)
{
    __shared__ __align__(16) signed char Alds[5 * 4096];   // plane p: p*4096 + rg*1024
    __shared__ __align__(16) signed char Blds[5 * 8192];   // plane q: q*8192 + ctl*1024

    const int tid = threadIdx.x;
    const int nMB = MCHUNK / 64;           // 248
    const int bm  = blockIdx.x % nMB;
    const int bnk = blockIdx.x / nMB;      // 0..3 (128-col blocks)
    const int m0 = bm * 64, n0 = bnk * 128;

    // --- A digitize/staging map: thread -> (row rA 0..63, k-quad kqA, 4B qtr jq)
    const int rA  = tid & 63;
    const int gA  = tid >> 6;              // 0..15
    const int kqA = gA & 3;
    const int jq  = gA >> 2;               // 0..3
    const int mA  = m0 + rA;
    const int bA  = b_base + mA / T_STEPS;
    const int tA  = mA % T_STEPS;
    const float* xp = x + (size_t)bA * CIN * WSLEN + tA * CSTRIDE;
    const int awb  = ((rA >> 4) << 10) + ((rA & 15) + kqA * 16) * 16 + jq * 4;
    const int kloc = kqA * 16 + jq * 4;    // k offset within the 64-wide tile

    // --- B staging map: 2560 16B slots/kt; thread covers slots tid, 1024+tid,
    //     and (tid<512) 2048+tid. slot s -> q=s>>9, ctl=(s&511)>>6, sl=s&63.
    const int ctl0 = (tid & 511) >> 6, sl0 = tid & 63;
    const int q0   = tid >> 9;                         // 0..1
    const int q1   = 2 + (tid >> 9);                   // 2..3
    const size_t cb_k = ((size_t)(bnk * 8)) << 10;
    const signed char* Bp0 = Bd + (size_t)q0 * 1048576 + cb_k + ctl0 * 1024 + sl0 * 16;
    const signed char* Bp1 = Bd + (size_t)q1 * 1048576 + cb_k + ctl0 * 1024 + sl0 * 16;
    const int ctl2 = tid >> 6, sl2 = tid & 63;         // only tid<512: ctl 0..7
    const signed char* Bp2 = Bd + (size_t)4 * 1048576 + cb_k + ctl2 * 1024 + sl2 * 16;
    const int ldsB0 = q0 * 8192 + ctl0 * 1024 + sl0 * 16;
    const int ldsB1 = q1 * 8192 + ctl0 * 1024 + sl0 * 16;
    const int ldsB2 = 4 * 8192 + ctl2 * 1024 + sl2 * 16;

    // --- MFMA map: wave = 16 rows x 32 cols ---
    const int wv  = tid >> 6;
    const int l   = tid & 63;
    const int rgM = wv >> 2;               // row group 0..3
    const int cw  = wv & 3;                // col pair: tiles cw*2 + s

    v4i acc[2][5];                         // [subtile][diagonal]
    #pragma unroll
    for (int s = 0; s < 2; ++s)
        #pragma unroll
        for (int d = 0; d < 5; ++d) acc[s][d] = (v4i){0, 0, 0, 0};

    // ---- prologue: issue tile-0 global loads (NAMED scalars) ----
    uint4 sb0, sb1, sb2;
    float4 sxa;
    sb0 = *(const uint4*)(Bp0);
    sb1 = *(const uint4*)(Bp1);
    if (tid < 512) sb2 = *(const uint4*)(Bp2);
    sxa = *(const float4*)(xp + (kloc >> 5) * WSLEN + (kloc & 31));

    for (int kt = 0; kt < 32; ++kt) {
        // digitize A (s_A = 8): 4 elements -> 4B per plane
        unsigned int pa[5];
        dig5(make_float4(sxa.x * 0.125f, sxa.y * 0.125f, sxa.z * 0.125f, sxa.w * 0.125f), pa);

        __syncthreads();                   // previous fragment reads complete
        #pragma unroll
        for (int p = 0; p < 5; ++p)
            *(unsigned int*)(Alds + p * 4096 + awb) = pa[p];
        *(uint4*)(Blds + ldsB0) = sb0;
        *(uint4*)(Blds + ldsB1) = sb1;
        if (tid < 512) *(uint4*)(Blds + ldsB2) = sb2;

        // issue next tile's global loads
        if (kt + 1 < 32) {
            size_t ko = (size_t)(kt + 1) * 32768;
            sb0 = *(const uint4*)(Bp0 + ko);
            sb1 = *(const uint4*)(Bp1 + ko);
            if (tid < 512) sb2 = *(const uint4*)(Bp2 + ko);
            int gk = (kt + 1) * 64 + kloc;
            sxa = *(const float4*)(xp + (gk >> 5) * WSLEN + (gk & 31));
        }
        __syncthreads();                   // staged data visible

        v4i aF[5];
        #pragma unroll
        for (int p = 0; p < 5; ++p)
            aF[p] = *(const v4i*)(Alds + p * 4096 + (rgM << 10) + (l << 4));

        #define MF(A_, B_, C_) __builtin_amdgcn_mfma_i32_16x16x64_i8(A_, B_, C_, 0, 0, 0)
        #pragma unroll
        for (int s = 0; s < 2; ++s) {
            const signed char* bb = Blds + ((cw * 2 + s) << 10) + (l << 4);
            v4i b0 = *(const v4i*)(bb);
            v4i b1 = *(const v4i*)(bb + 8192);
            v4i b2 = *(const v4i*)(bb + 16384);
            v4i b3 = *(const v4i*)(bb + 24576);
            v4i b4 = *(const v4i*)(bb + 32768);
            acc[s][0] = MF(aF[0], b0, acc[s][0]);
            acc[s][1] = MF(aF[1], b0, MF(aF[0], b1, acc[s][1]));
            acc[s][2] = MF(aF[2], b0, MF(aF[1], b1, MF(aF[0], b2, acc[s][2])));
            acc[s][3] = MF(aF[3], b0, MF(aF[2], b1, MF(aF[1], b2, MF(aF[0], b3, acc[s][3]))));
            acc[s][4] = MF(aF[4], b0, MF(aF[3], b1, MF(aF[2], b2, MF(aF[1], b3, MF(aF[0], b4, acc[s][4])))));
        }
        #undef MF
    }

    // ---- epilogue: exact f64 reconstruction + conv bias + BN, store f64 ----
    const int l15 = l & 15;
    const int rq  = l >> 4;
    #pragma unroll
    for (int s = 0; s < 2; ++s) {
        const int co = n0 + (cw * 2 + s) * 16 + l15;
        const double g   = (double)bn_gamma[co];
        const double be  = (double)bn_beta[co];
        const double mn  = (double)bn_mean[co];
        const double vr  = (double)bn_var[co];
        const double cb  = (double)conv_b[co];
        const double inv = 1.0 / sqrt(vr + 1e-5);
        #pragma unroll
        for (int r = 0; r < 4; ++r) {
            double v = (double)acc[s][0][r] * 0x1p-13
                     + (double)acc[s][1][r] * 0x1p-20
                     + (double)acc[s][2][r] * 0x1p-27
                     + (double)acc[s][3][r] * 0x1p-34
                     + (double)acc[s][4][r] * 0x1p-41;
            int m = m0 + rgM * 16 + rq * 4 + r;
            seq[(size_t)m * COUT + co] = g * (v + cb - mn) * inv + be;
        }
    }
}

// ---------------------------------------------------------------------------
// SNN scan v3 (unchanged): 1 batch row per block, 512 threads.
// ---------------------------------------------------------------------------
__global__ __launch_bounds__(512, 4) void snn_scan_v3_kernel(
    const double* __restrict__ seq, const float* __restrict__ fc1wT,
    const float* __restrict__ fc1_b, const float* __restrict__ fc2_w,
    const float* __restrict__ fc2_b, const float* __restrict__ beta_enc,
    const float* __restrict__ beta_hid, const float* __restrict__ beta_out,
    float* __restrict__ out, int b_base)
{
    __shared__ int   list[COUT];
    __shared__ int   wcnt[8];
    __shared__ double red[8][2];

    const int tid  = threadIdx.x;
    const int lane = tid & 63;
    const int wave = tid >> 6;
    const int row  = blockIdx.x;
    const int brow = b_base + row;

    const double be  = clip01d((double)beta_enc[tid]);
    const double bh  = clip01d((double)beta_hid[tid]);
    const double f1b = (double)fc1_b[tid];
    const double w2a = (double)fc2_w[tid];
    const double w2b = (double)fc2_w[COUT + tid];

    double bo = 0.0, f2b = 0.0, om = 0.0;
    if (tid < 2) { bo = clip01d((double)beta_out[tid]); f2b = (double)fc2_b[tid]; }

    double em = 0.0, hm = 0.0;
    const double* sp = seq + (size_t)row * T_STEPS * COUT + tid;

    for (int t = 0; t < T_STEPS; ++t) {
        double inp = sp[(size_t)t * COUT];
        double e = be * em + inp - ((em > 1.0) ? 1.0 : 0.0);
        em = e;
        bool spike = (e > 1.0);

        unsigned long long mask = __ballot(spike);
        if (lane == 0) wcnt[wave] = __popcll(mask);
        __syncthreads();

        int base = 0, cnt = 0;
        #pragma unroll
        for (int w = 0; w < 8; ++w) {
            int v = wcnt[w];
            base += (w < wave) ? v : 0;
            cnt  += v;
        }
        if (spike) {
            int pos = base + __popcll(mask & ((1ull << lane) - 1ull));
            list[pos] = tid;
        }
        __syncthreads();

        double s0 = 0.0, s1 = 0.0, s2 = 0.0, s3 = 0.0;
        const float* fw = fc1wT + tid;
        int i = 0;
        for (; i + 4 <= cnt; i += 4) {
            int cA = list[i], cB = list[i + 1], cC = list[i + 2], cD = list[i + 3];
            float wA = fw[(size_t)cA * COUT];
            float wB = fw[(size_t)cB * COUT];
            float wC = fw[(size_t)cC * COUT];
            float wD = fw[(size_t)cD * COUT];
            s0 += (double)wA;
            s1 += (double)wB;
            s2 += (double)wC;
            s3 += (double)wD;
        }
        for (; i < cnt; ++i) s0 += (double)fw[(size_t)list[i] * COUT];
        double cur1 = ((s0 + s1) + (s2 + s3)) + f1b;

        double h = bh * hm + cur1 - ((hm > 1.0) ? 1.0 : 0.0);
        hm = h;
        double sh = (h > 1.0) ? 1.0 : 0.0;
        double p0 = sh * w2a;
        double p1 = sh * w2b;
        #pragma unroll
        for (int off = 32; off > 0; off >>= 1) {
            p0 += __shfl_down(p0, off);
            p1 += __shfl_down(p1, off);
        }
        if (lane == 0) { red[wave][0] = p0; red[wave][1] = p1; }
        __syncthreads();

        if (tid < 2) {
            double cur2 = f2b;
            #pragma unroll
            for (int w = 0; w < 8; ++w) cur2 += red[w][tid];
            double o = bo * om + cur2 - ((om > 1.0) ? 1.0 : 0.0);
            om = o;
            float so = (o > 1.0) ? 1.0f : 0.0f;
            int bidx = brow * 2 + tid;
            out[2048 + t * 2048 + bidx] = so;               // spk_rec
            out[2048 + 63488 + t * 2048 + bidx] = (float)o; // mem_rec
            if (t == T_STEPS - 1) out[bidx] = (float)o;     // final om
        }
    }
}

// ---------------------------------------------------------------------------
extern "C" void kernel_launch(void* const* d_in, const int* in_sizes, int n_in,
                              void* d_out, int out_size, void* d_ws, size_t ws_size,
                              hipStream_t stream)
{
    const float* x        = (const float*)d_in[0];
    const float* conv_w   = (const float*)d_in[1];
    const float* conv_b   = (const float*)d_in[2];
    const float* bn_gamma = (const float*)d_in[3];
    const float* bn_beta  = (const float*)d_in[4];
    const float* bn_mean  = (const float*)d_in[5];
    const float* bn_var   = (const float*)d_in[6];
    const float* fc1_w    = (const float*)d_in[7];
    const float* fc1_b    = (const float*)d_in[8];
    const float* fc2_w    = (const float*)d_in[9];
    const float* fc2_b    = (const float*)d_in[10];
    const float* beta_enc = (const float*)d_in[11];
    const float* beta_hid = (const float*)d_in[12];
    const float* beta_out = (const float*)d_in[13];
    float* out = (float*)d_out;

    // ws layout: Bd 5 MB | fc1wT 1 MB | seq 65 MB  (71.25 MB total)
    signed char* Bd    = (signed char*)d_ws;
    float*       fc1wT = (float*)((char*)d_ws + 5 * 1048576);
    double*      seq   = (double*)((char*)d_ws + 6 * 1048576);

    prep_fc1_kernel<<<1024, 256, 0, stream>>>(fc1_w, fc1wT);
    prep_bd_kernel<<<1024, 256, 0, stream>>>(conv_w, Bd);

    for (int chunk = 0; chunk < 2; ++chunk) {
        int b_base = chunk * BCHUNK;
        conv_bn_i8v5_kernel<<<(MCHUNK / 64) * (COUT / 128), 1024, 0, stream>>>(
            x, Bd, conv_b, bn_gamma, bn_beta, bn_mean, bn_var, seq, b_base);
        snn_scan_v3_kernel<<<BCHUNK, 512, 0, stream>>>(
            seq, fc1wT, fc1_b, fc2_w, fc2_b, beta_enc, beta_hid, beta_out, out, b_base);
    }
}

// Round 12
// 867.602 us; speedup vs baseline: 2.0090x; 1.0161x over previous
//
#include <hip/hip_runtime.h>

#define T_STEPS 31
#define CIN     64
#define COUT    512
#define WSLEN   512
#define CSTRIDE 16
#define KRED    2048                 // CIN*32
#define NBATCH  1024
#define BCHUNK  512                  // batch rows per pass (seq buffer reuse)
#define MCHUNK  (BCHUNK * T_STEPS)   // 15872 rows per pass

typedef int v4i __attribute__((ext_vector_type(4)));

__device__ __forceinline__ double clip01d(double v) { return fmin(fmax(v, 0.0), 1.0); }

// Async global->LDS 16B copy: per-lane global src, wave-uniform LDS base
// (HW writes lds_base + lane*16). Size must be the literal 16.
__device__ __forceinline__ void gl_lds16(const void* g, void* l) {
    __builtin_amdgcn_global_load_lds(
        (const __attribute__((address_space(1))) void*)g,
        (__attribute__((address_space(3))) void*)l, 16, 0, 0);
}

// ---------------------------------------------------------------------------
// Digitize 4 pre-scaled floats (|v| < 0.75) into 5 base-128 digits each,
// packed one byte per element per plane. Exact extraction (proven R8).
// ---------------------------------------------------------------------------
__device__ __forceinline__ void dig5(float4 f, unsigned int w[5]) {
    float vv[4] = {f.x, f.y, f.z, f.w};
    unsigned int w0 = 0, w1 = 0, w2 = 0, w3 = 0, w4 = 0;
    #pragma unroll
    for (int e = 0; e < 4; ++e) {
        float v  = vv[e];
        float c0 = rintf(v * 16384.0f);                     // d1*128+d2
        float r1 = fmaf(c0, -6.103515625e-05f, v);          // v - c0*2^-14
        float c1 = rintf(r1 * 268435456.0f);                // d3*128+d4
        float r2 = fmaf(c1, -3.725290298461914e-09f, r1);   // r1 - c1*2^-28
        float c2 = rintf(r2 * 34359738368.0f);              // d5 = r2*2^35
        int i0 = (int)c0, i1 = (int)c1, i2 = (int)c2;
        int d2 = ((i0 + 64) & 127) - 64;                    // balanced split
        int d1 = (i0 - d2) >> 7;
        int d4 = ((i1 + 64) & 127) - 64;
        int d3 = (i1 - d4) >> 7;
        w0 |= (unsigned int)(d1 & 255) << (8 * e);
        w1 |= (unsigned int)(d2 & 255) << (8 * e);
        w2 |= (unsigned int)(d3 & 255) << (8 * e);
        w3 |= (unsigned int)(d4 & 255) << (8 * e);
        w4 |= (unsigned int)(i2 & 255) << (8 * e);
    }
    w[0] = w0; w[1] = w1; w[2] = w2; w[3] = w3; w[4] = w4;
}

// ---------------------------------------------------------------------------
// Prep 1: transpose fc1_w [co][c] -> fc1wT [c][co]  (f32, exact)
// ---------------------------------------------------------------------------
__global__ __launch_bounds__(256) void prep_fc1_kernel(
    const float* __restrict__ fc1_w, float* __restrict__ fc1wT)
{
    int idx = blockIdx.x * 256 + threadIdx.x;      // 262144 threads
    int co = idx & 511;
    int r  = idx >> 9;
    fc1wT[idx] = fc1_w[co * COUT + r];
}

// ---------------------------------------------------------------------------
// Prep 2: digitize conv_w (scaled by 4 = 1/s_B) into 5 i8 digit planes in
// mfma_i32_16x16x64_i8 B-fragment order (unchanged from R8).
// ---------------------------------------------------------------------------
__global__ __launch_bounds__(256) void prep_bd_kernel(
    const float* __restrict__ conv_w, signed char* __restrict__ Bd)
{
    int t  = blockIdx.x * 256 + threadIdx.x;       // 262144 threads
    int k4 = (t & 511) << 2;                       // 0..2044
    int co = t >> 9;                               // 0..511
    float4 w4 = *(const float4*)(conv_w + (size_t)co * KRED + k4);
    float4 v4 = make_float4(w4.x * 4.0f, w4.y * 4.0f, w4.z * 4.0f, w4.w * 4.0f);
    unsigned int pk[5];
    dig5(v4, pk);
    int off = (((k4 >> 6) * 32 + (co >> 4)) << 10)
            + ((co & 15) + ((k4 >> 4) & 3) * 16) * 16 + (k4 & 15);
    #pragma unroll
    for (int q = 0; q < 5; ++q)
        *(unsigned int*)(Bd + q * 1048576 + off) = pk[q];
}

// ---------------------------------------------------------------------------
// Conv1d + BN via exact i8-digit MFMA, v6: block = 512 thr (8 waves),
// 32 rows x 128 cols (R10's geometry, which PASSED correctness).
// Wave = 16 rows x 32 cols = 2 subtiles, acc[2][5]=40 accums.
// B staged via async global_load_lds (fragment-ordered planes are linear
// 1KB-block copies) -> ZERO B staging registers (R10's spill surface gone).
// LDS 50 KB -> 2-3 blocks/CU, 8-wave barriers (vs R11's 16-wave monolith).
// ---------------------------------------------------------------------------
__global__ __launch_bounds__(512) void conv_bn_i8v6_kernel(
    const float* __restrict__ x, const signed char* __restrict__ Bd,
    const float* __restrict__ conv_b,
    const float* __restrict__ bn_gamma, const float* __restrict__ bn_beta,
    const float* __restrict__ bn_mean,  const float* __restrict__ bn_var,
    double* __restrict__ seq, int b_base)
{
    __shared__ __align__(16) signed char Alds[5 * 2048];   // plane p: p*2048 + rg*1024
    __shared__ __align__(16) signed char Blds[5 * 8192];   // plane q: q*8192 + ctl*1024

    const int tid = threadIdx.x;
    const int nMB = MCHUNK / 32;           // 496
    const int bm  = blockIdx.x % nMB;
    const int bnk = blockIdx.x / nMB;      // 0..3 (128-col blocks)
    const int m0 = bm * 32, n0 = bnk * 128;

    // --- A digitize/staging map (identical to R10) ---
    const int rA  = tid & 31;
    const int gA  = tid >> 5;              // 0..15
    const int kqA = gA & 3;
    const int jq  = gA >> 2;               // 0..3
    const int mA  = m0 + rA;
    const int bA  = b_base + mA / T_STEPS;
    const int tA  = mA % T_STEPS;
    const float* xp = x + (size_t)bA * CIN * WSLEN + tA * CSTRIDE;
    const int awb  = ((rA >> 4) << 10) + ((rA & 15) + kqA * 16) * 16 + jq * 4;
    const int kloc = kqA * 16 + jq * 4;    // k offset within the 64-wide tile

    // --- MFMA map: wave = 16 rows x 32 cols (2 subtiles) ---
    const int wv  = tid >> 6;
    const int l   = tid & 63;
    const int rgM = wv >> 2;               // row group 0..1
    const int cw  = wv & 3;                // col pair: tiles cw*2 + s

    // --- B async-copy map: wave wv covers 16B-slot groups s = wv*5 + i,
    //     i=0..4; slot s -> plane q=s>>3, local col-tile ctl=s&7.
    //     glob per-lane = base + l*16; LDS base wave-uniform.

    v4i acc[2][5];                         // [subtile][diagonal]
    #pragma unroll
    for (int s = 0; s < 2; ++s)
        #pragma unroll
        for (int d = 0; d < 5; ++d) acc[s][d] = (v4i){0, 0, 0, 0};

    // ---- prologue: A prefetch for tile 0 ----
    float4 sxa = *(const float4*)(xp + (kloc >> 5) * WSLEN + (kloc & 31));

    for (int kt = 0; kt < 32; ++kt) {
        // digitize A (s_A = 8): 4 elements -> 4B per plane
        unsigned int pa[5];
        dig5(make_float4(sxa.x * 0.125f, sxa.y * 0.125f, sxa.z * 0.125f, sxa.w * 0.125f), pa);

        __syncthreads();                   // previous fragment reads complete
        #pragma unroll
        for (int p = 0; p < 5; ++p)
            *(unsigned int*)(Alds + p * 2048 + awb) = pa[p];

        // async B copy for this kt (5 x 1KB per wave, zero VGPR staging)
        #pragma unroll
        for (int i = 0; i < 5; ++i) {
            const int s   = wv * 5 + i;
            const int q   = s >> 3;
            const int ctl = s & 7;
            const signed char* gsrc = Bd + (size_t)q * 1048576
                + (((size_t)(kt * 32 + bnk * 8 + ctl)) << 10) + l * 16;
            gl_lds16(gsrc, Blds + q * 8192 + ctl * 1024);
        }

        // prefetch next x tile
        if (kt + 1 < 32) {
            int gk = (kt + 1) * 64 + kloc;
            sxa = *(const float4*)(xp + (gk >> 5) * WSLEN + (gk & 31));
        }
        __syncthreads();                   // drains vmcnt+lgkmcnt: A,B visible

        v4i aF[5];
        #pragma unroll
        for (int p = 0; p < 5; ++p)
            aF[p] = *(const v4i*)(Alds + p * 2048 + (rgM << 10) + (l << 4));

        #define MF(A_, B_, C_) __builtin_amdgcn_mfma_i32_16x16x64_i8(A_, B_, C_, 0, 0, 0)
        #pragma unroll
        for (int s = 0; s < 2; ++s) {
            const signed char* bb = Blds + ((cw * 2 + s) << 10) + (l << 4);
            v4i b0 = *(const v4i*)(bb);
            v4i b1 = *(const v4i*)(bb + 8192);
            v4i b2 = *(const v4i*)(bb + 16384);
            v4i b3 = *(const v4i*)(bb + 24576);
            v4i b4 = *(const v4i*)(bb + 32768);
            acc[s][0] = MF(aF[0], b0, acc[s][0]);
            acc[s][1] = MF(aF[1], b0, MF(aF[0], b1, acc[s][1]));
            acc[s][2] = MF(aF[2], b0, MF(aF[1], b1, MF(aF[0], b2, acc[s][2])));
            acc[s][3] = MF(aF[3], b0, MF(aF[2], b1, MF(aF[1], b2, MF(aF[0], b3, acc[s][3]))));
            acc[s][4] = MF(aF[4], b0, MF(aF[3], b1, MF(aF[2], b2, MF(aF[1], b3, MF(aF[0], b4, acc[s][4])))));
        }
        #undef MF
    }

    // ---- epilogue: exact f64 reconstruction + conv bias + BN, store f64 ----
    const int l15 = l & 15;
    const int rq  = l >> 4;
    #pragma unroll
    for (int s = 0; s < 2; ++s) {
        const int co = n0 + (cw * 2 + s) * 16 + l15;
        const double g   = (double)bn_gamma[co];
        const double be  = (double)bn_beta[co];
        const double mn  = (double)bn_mean[co];
        const double vr  = (double)bn_var[co];
        const double cb  = (double)conv_b[co];
        const double inv = 1.0 / sqrt(vr + 1e-5);
        #pragma unroll
        for (int r = 0; r < 4; ++r) {
            double v = (double)acc[s][0][r] * 0x1p-13
                     + (double)acc[s][1][r] * 0x1p-20
                     + (double)acc[s][2][r] * 0x1p-27
                     + (double)acc[s][3][r] * 0x1p-34
                     + (double)acc[s][4][r] * 0x1p-41;
            int m = m0 + rgM * 16 + rq * 4 + r;
            seq[(size_t)m * COUT + co] = g * (v + cb - mn) * inv + be;
        }
    }
}

// ---------------------------------------------------------------------------
// SNN scan v3 (unchanged): 1 batch row per block, 512 threads.
// ---------------------------------------------------------------------------
__global__ __launch_bounds__(512, 4) void snn_scan_v3_kernel(
    const double* __restrict__ seq, const float* __restrict__ fc1wT,
    const float* __restrict__ fc1_b, const float* __restrict__ fc2_w,
    const float* __restrict__ fc2_b, const float* __restrict__ beta_enc,
    const float* __restrict__ beta_hid, const float* __restrict__ beta_out,
    float* __restrict__ out, int b_base)
{
    __shared__ int   list[COUT];
    __shared__ int   wcnt[8];
    __shared__ double red[8][2];

    const int tid  = threadIdx.x;
    const int lane = tid & 63;
    const int wave = tid >> 6;
    const int row  = blockIdx.x;
    const int brow = b_base + row;

    const double be  = clip01d((double)beta_enc[tid]);
    const double bh  = clip01d((double)beta_hid[tid]);
    const double f1b = (double)fc1_b[tid];
    const double w2a = (double)fc2_w[tid];
    const double w2b = (double)fc2_w[COUT + tid];

    double bo = 0.0, f2b = 0.0, om = 0.0;
    if (tid < 2) { bo = clip01d((double)beta_out[tid]); f2b = (double)fc2_b[tid]; }

    double em = 0.0, hm = 0.0;
    const double* sp = seq + (size_t)row * T_STEPS * COUT + tid;

    for (int t = 0; t < T_STEPS; ++t) {
        double inp = sp[(size_t)t * COUT];
        double e = be * em + inp - ((em > 1.0) ? 1.0 : 0.0);
        em = e;
        bool spike = (e > 1.0);

        unsigned long long mask = __ballot(spike);
        if (lane == 0) wcnt[wave] = __popcll(mask);
        __syncthreads();

        int base = 0, cnt = 0;
        #pragma unroll
        for (int w = 0; w < 8; ++w) {
            int v = wcnt[w];
            base += (w < wave) ? v : 0;
            cnt  += v;
        }
        if (spike) {
            int pos = base + __popcll(mask & ((1ull << lane) - 1ull));
            list[pos] = tid;
        }
        __syncthreads();

        double s0 = 0.0, s1 = 0.0, s2 = 0.0, s3 = 0.0;
        const float* fw = fc1wT + tid;
        int i = 0;
        for (; i + 4 <= cnt; i += 4) {
            int cA = list[i], cB = list[i + 1], cC = list[i + 2], cD = list[i + 3];
            float wA = fw[(size_t)cA * COUT];
            float wB = fw[(size_t)cB * COUT];
            float wC = fw[(size_t)cC * COUT];
            float wD = fw[(size_t)cD * COUT];
            s0 += (double)wA;
            s1 += (double)wB;
            s2 += (double)wC;
            s3 += (double)wD;
        }
        for (; i < cnt; ++i) s0 += (double)fw[(size_t)list[i] * COUT];
        double cur1 = ((s0 + s1) + (s2 + s3)) + f1b;

        double h = bh * hm + cur1 - ((hm > 1.0) ? 1.0 : 0.0);
        hm = h;
        double sh = (h > 1.0) ? 1.0 : 0.0;
        double p0 = sh * w2a;
        double p1 = sh * w2b;
        #pragma unroll
        for (int off = 32; off > 0; off >>= 1) {
            p0 += __shfl_down(p0, off);
            p1 += __shfl_down(p1, off);
        }
        if (lane == 0) { red[wave][0] = p0; red[wave][1] = p1; }
        __syncthreads();

        if (tid < 2) {
            double cur2 = f2b;
            #pragma unroll
            for (int w = 0; w < 8; ++w) cur2 += red[w][tid];
            double o = bo * om + cur2 - ((om > 1.0) ? 1.0 : 0.0);
            om = o;
            float so = (o > 1.0) ? 1.0f : 0.0f;
            int bidx = brow * 2 + tid;
            out[2048 + t * 2048 + bidx] = so;               // spk_rec
            out[2048 + 63488 + t * 2048 + bidx] = (float)o; // mem_rec
            if (t == T_STEPS - 1) out[bidx] = (float)o;     // final om
        }
    }
}

// ---------------------------------------------------------------------------
extern "C" void kernel_launch(void* const* d_in, const int* in_sizes, int n_in,
                              void* d_out, int out_size, void* d_ws, size_t ws_size,
                              hipStream_t stream)
{
    const float* x        = (const float*)d_in[0];
    const float* conv_w   = (const float*)d_in[1];
    const float* conv_b   = (const float*)d_in[2];
    const float* bn_gamma = (const float*)d_in[3];
    const float* bn_beta  = (const float*)d_in[4];
    const float* bn_mean  = (const float*)d_in[5];
    const float* bn_var   = (const float*)d_in[6];
    const float* fc1_w    = (const float*)d_in[7];
    const float* fc1_b    = (const float*)d_in[8];
    const float* fc2_w    = (const float*)d_in[9];
    const float* fc2_b    = (const float*)d_in[10];
    const float* beta_enc = (const float*)d_in[11];
    const float* beta_hid = (const float*)d_in[12];
    const float* beta_out = (const float*)d_in[13];
    float* out = (float*)d_out;

    // ws layout: Bd 5 MB | fc1wT 1 MB | seq 65 MB  (71.25 MB total)
    signed char* Bd    = (signed char*)d_ws;
    float*       fc1wT = (float*)((char*)d_ws + 5 * 1048576);
    double*      seq   = (double*)((char*)d_ws + 6 * 1048576);

    prep_fc1_kernel<<<1024, 256, 0, stream>>>(fc1_w, fc1wT);
    prep_bd_kernel<<<1024, 256, 0, stream>>>(conv_w, Bd);

    for (int chunk = 0; chunk < 2; ++chunk) {
        int b_base = chunk * BCHUNK;
        conv_bn_i8v6_kernel<<<(MCHUNK / 32) * (COUT / 128), 512, 0, stream>>>(
            x, Bd, conv_b, bn_gamma, bn_beta, bn_mean, bn_var, seq, b_base);
        snn_scan_v3_kernel<<<BCHUNK, 512, 0, stream>>>(
            seq, fc1wT, fc1_b, fc2_w, fc2_b, beta_enc, beta_hid, beta_out, out, b_base);
    }
}

// Round 13
// 712.372 us; speedup vs baseline: 2.4468x; 1.2179x over previous
//
#include <hip/hip_runtime.h>

#define T_STEPS 31
#define CIN     64
#define COUT    512
#define WSLEN   512
#define CSTRIDE 16
#define KRED    2048                 // CIN*32
#define NBATCH  1024
#define BCHUNK  512                  // batch rows per pass (seq buffer reuse)
#define MCHUNK  (BCHUNK * T_STEPS)   // 15872 rows per pass
#define NMT     (MCHUNK / 16)        // 992 m-tiles per chunk

typedef int v4i __attribute__((ext_vector_type(4)));

__device__ __forceinline__ double clip01d(double v) { return fmin(fmax(v, 0.0), 1.0); }

// Async global->LDS 16B copy: per-lane global src, wave-uniform LDS base
// (HW writes lds_base + lane*16). Size must be the literal 16.
__device__ __forceinline__ void gl_lds16(const void* g, void* l) {
    __builtin_amdgcn_global_load_lds(
        (const __attribute__((address_space(1))) void*)g,
        (__attribute__((address_space(3))) void*)l, 16, 0, 0);
}

// ---------------------------------------------------------------------------
// Digitize 4 pre-scaled floats (|v| < 0.99) into 5 base-128 digits each,
// packed one byte per element per plane. Exact extraction (proven R8).
// ---------------------------------------------------------------------------
__device__ __forceinline__ void dig5(float4 f, unsigned int w[5]) {
    float vv[4] = {f.x, f.y, f.z, f.w};
    unsigned int w0 = 0, w1 = 0, w2 = 0, w3 = 0, w4 = 0;
    #pragma unroll
    for (int e = 0; e < 4; ++e) {
        float v  = vv[e];
        float c0 = rintf(v * 16384.0f);                     // d1*128+d2
        float r1 = fmaf(c0, -6.103515625e-05f, v);          // v - c0*2^-14
        float c1 = rintf(r1 * 268435456.0f);                // d3*128+d4
        float r2 = fmaf(c1, -3.725290298461914e-09f, r1);   // r1 - c1*2^-28
        float c2 = rintf(r2 * 34359738368.0f);              // d5 = r2*2^35
        int i0 = (int)c0, i1 = (int)c1, i2 = (int)c2;
        int d2 = ((i0 + 64) & 127) - 64;                    // balanced split
        int d1 = (i0 - d2) >> 7;
        int d4 = ((i1 + 64) & 127) - 64;
        int d3 = (i1 - d4) >> 7;
        w0 |= (unsigned int)(d1 & 255) << (8 * e);
        w1 |= (unsigned int)(d2 & 255) << (8 * e);
        w2 |= (unsigned int)(d3 & 255) << (8 * e);
        w3 |= (unsigned int)(d4 & 255) << (8 * e);
        w4 |= (unsigned int)(i2 & 255) << (8 * e);
    }
    w[0] = w0; w[1] = w1; w[2] = w2; w[3] = w3; w[4] = w4;
}

// ---------------------------------------------------------------------------
// Prep: transpose fc1_w [co][c] -> fc1wT [c][co]  (fallback path only)
// ---------------------------------------------------------------------------
__global__ __launch_bounds__(256) void prep_fc1_kernel(
    const float* __restrict__ fc1_w, float* __restrict__ fc1wT)
{
    int idx = blockIdx.x * 256 + threadIdx.x;
    int co = idx & 511;
    int r  = idx >> 9;
    fc1wT[idx] = fc1_w[co * COUT + r];
}

// ---------------------------------------------------------------------------
// Prep: digitize conv_w (x4) into 5 i8 digit planes, B-fragment order.
// ---------------------------------------------------------------------------
__global__ __launch_bounds__(256) void prep_bd_kernel(
    const float* __restrict__ conv_w, signed char* __restrict__ Bd)
{
    int t  = blockIdx.x * 256 + threadIdx.x;       // 262144 threads
    int k4 = (t & 511) << 2;
    int co = t >> 9;
    float4 w4 = *(const float4*)(conv_w + (size_t)co * KRED + k4);
    float4 v4 = make_float4(w4.x * 4.0f, w4.y * 4.0f, w4.z * 4.0f, w4.w * 4.0f);
    unsigned int pk[5];
    dig5(v4, pk);
    int off = (((k4 >> 6) * 32 + (co >> 4)) << 10)
            + ((co & 15) + ((k4 >> 4) & 3) * 16) * 16 + (k4 & 15);
    #pragma unroll
    for (int q = 0; q < 5; ++q)
        *(unsigned int*)(Bd + q * 1048576 + off) = pk[q];
}

// ---------------------------------------------------------------------------
// Prep: digitize fc1_w (x4) into 5 i8 digit planes, B-fragment order.
// Plane q (256 KB): block (kt=k>>6, ct=co>>4) of 1 KB.
// ---------------------------------------------------------------------------
__global__ __launch_bounds__(256) void prep_fd_kernel(
    const float* __restrict__ fc1_w, signed char* __restrict__ Fd)
{
    int t  = blockIdx.x * 256 + threadIdx.x;       // 65536 threads
    int k4 = (t & 127) << 2;                       // 0..508
    int co = t >> 7;                               // 0..511
    float4 w4 = *(const float4*)(fc1_w + (size_t)co * COUT + k4);
    float4 v4 = make_float4(w4.x * 4.0f, w4.y * 4.0f, w4.z * 4.0f, w4.w * 4.0f);
    unsigned int pk[5];
    dig5(v4, pk);
    int off = (((k4 >> 6) * 32 + (co >> 4)) << 10)
            + ((co & 15) + ((k4 >> 4) & 3) * 16) * 16 + (k4 & 15);
    #pragma unroll
    for (int q = 0; q < 5; ++q)
        *(unsigned int*)(Fd + q * 262144 + off) = pk[q];
}

// ---------------------------------------------------------------------------
// Conv1d + BN via exact i8-digit MFMA (v6, unchanged from R12).
// ---------------------------------------------------------------------------
__global__ __launch_bounds__(512) void conv_bn_i8v6_kernel(
    const float* __restrict__ x, const signed char* __restrict__ Bd,
    const float* __restrict__ conv_b,
    const float* __restrict__ bn_gamma, const float* __restrict__ bn_beta,
    const float* __restrict__ bn_mean,  const float* __restrict__ bn_var,
    double* __restrict__ seq, int b_base)
{
    __shared__ __align__(16) signed char Alds[5 * 2048];
    __shared__ __align__(16) signed char Blds[5 * 8192];

    const int tid = threadIdx.x;
    const int nMB = MCHUNK / 32;           // 496
    const int bm  = blockIdx.x % nMB;
    const int bnk = blockIdx.x / nMB;
    const int m0 = bm * 32, n0 = bnk * 128;

    const int rA  = tid & 31;
    const int gA  = tid >> 5;
    const int kqA = gA & 3;
    const int jq  = gA >> 2;
    const int mA  = m0 + rA;
    const int bA  = b_base + mA / T_STEPS;
    const int tA  = mA % T_STEPS;
    const float* xp = x + (size_t)bA * CIN * WSLEN + tA * CSTRIDE;
    const int awb  = ((rA >> 4) << 10) + ((rA & 15) + kqA * 16) * 16 + jq * 4;
    const int kloc = kqA * 16 + jq * 4;

    const int wv  = tid >> 6;
    const int l   = tid & 63;
    const int rgM = wv >> 2;
    const int cw  = wv & 3;

    v4i acc[2][5];
    #pragma unroll
    for (int s = 0; s < 2; ++s)
        #pragma unroll
        for (int d = 0; d < 5; ++d) acc[s][d] = (v4i){0, 0, 0, 0};

    float4 sxa = *(const float4*)(xp + (kloc >> 5) * WSLEN + (kloc & 31));

    for (int kt = 0; kt < 32; ++kt) {
        unsigned int pa[5];
        dig5(make_float4(sxa.x * 0.125f, sxa.y * 0.125f, sxa.z * 0.125f, sxa.w * 0.125f), pa);

        __syncthreads();
        #pragma unroll
        for (int p = 0; p < 5; ++p)
            *(unsigned int*)(Alds + p * 2048 + awb) = pa[p];

        #pragma unroll
        for (int i = 0; i < 5; ++i) {
            const int s   = wv * 5 + i;
            const int q   = s >> 3;
            const int ctl = s & 7;
            const signed char* gsrc = Bd + (size_t)q * 1048576
                + (((size_t)(kt * 32 + bnk * 8 + ctl)) << 10) + l * 16;
            gl_lds16(gsrc, Blds + q * 8192 + ctl * 1024);
        }

        if (kt + 1 < 32) {
            int gk = (kt + 1) * 64 + kloc;
            sxa = *(const float4*)(xp + (gk >> 5) * WSLEN + (gk & 31));
        }
        __syncthreads();

        v4i aF[5];
        #pragma unroll
        for (int p = 0; p < 5; ++p)
            aF[p] = *(const v4i*)(Alds + p * 2048 + (rgM << 10) + (l << 4));

        #define MF(A_, B_, C_) __builtin_amdgcn_mfma_i32_16x16x64_i8(A_, B_, C_, 0, 0, 0)
        #pragma unroll
        for (int s = 0; s < 2; ++s) {
            const signed char* bb = Blds + ((cw * 2 + s) << 10) + (l << 4);
            v4i b0 = *(const v4i*)(bb);
            v4i b1 = *(const v4i*)(bb + 8192);
            v4i b2 = *(const v4i*)(bb + 16384);
            v4i b3 = *(const v4i*)(bb + 24576);
            v4i b4 = *(const v4i*)(bb + 32768);
            acc[s][0] = MF(aF[0], b0, acc[s][0]);
            acc[s][1] = MF(aF[1], b0, MF(aF[0], b1, acc[s][1]));
            acc[s][2] = MF(aF[2], b0, MF(aF[1], b1, MF(aF[0], b2, acc[s][2])));
            acc[s][3] = MF(aF[3], b0, MF(aF[2], b1, MF(aF[1], b2, MF(aF[0], b3, acc[s][3]))));
            acc[s][4] = MF(aF[4], b0, MF(aF[3], b1, MF(aF[2], b2, MF(aF[1], b3, MF(aF[0], b4, acc[s][4])))));
        }
        #undef MF
    }

    const int l15 = l & 15;
    const int rq  = l >> 4;
    #pragma unroll
    for (int s = 0; s < 2; ++s) {
        const int co = n0 + (cw * 2 + s) * 16 + l15;
        const double g   = (double)bn_gamma[co];
        const double be  = (double)bn_beta[co];
        const double mn  = (double)bn_mean[co];
        const double vr  = (double)bn_var[co];
        const double cb  = (double)conv_b[co];
        const double inv = 1.0 / sqrt(vr + 1e-5);
        #pragma unroll
        for (int r = 0; r < 4; ++r) {
            double v = (double)acc[s][0][r] * 0x1p-13
                     + (double)acc[s][1][r] * 0x1p-20
                     + (double)acc[s][2][r] * 0x1p-27
                     + (double)acc[s][3][r] * 0x1p-34
                     + (double)acc[s][4][r] * 0x1p-41;
            int m = m0 + rgM * 16 + rq * 4 + r;
            seq[(size_t)m * COUT + co] = g * (v + cb - mn) * inv + be;
        }
    }
}

// ---------------------------------------------------------------------------
// Encoder scan: per-(b,c) 31-step em recurrence; spikes written as i8 bytes
// in MFMA-A-fragment order: Sd[((c>>6)*NMT + (m>>4))*1024
//                              + ((m&15) + ((c>>4)&3)*16)*16 + (c&15)].
// ---------------------------------------------------------------------------
__global__ __launch_bounds__(512) void enc_scan_kernel(
    const double* __restrict__ seq, const float* __restrict__ beta_enc,
    signed char* __restrict__ Sd)
{
    const int c = threadIdx.x;
    const int b = blockIdx.x;              // local row within chunk
    const double be = clip01d((double)beta_enc[c]);
    const double* sp = seq + (size_t)b * T_STEPS * COUT + c;
    const size_t cblk = (size_t)(c >> 6) * NMT;
    const int    coff = ((c >> 4) & 3) * 16;
    const int    j    = c & 15;
    double em = 0.0;
    for (int t = 0; t < T_STEPS; ++t) {
        double e = be * em + sp[(size_t)t * COUT] - ((em > 1.0) ? 1.0 : 0.0);
        em = e;
        int m = b * T_STEPS + t;
        Sd[((cblk + (m >> 4)) << 10) + ((m & 15) + coff) * 16 + j] =
            (e > 1.0) ? (signed char)1 : (signed char)0;
    }
}

// ---------------------------------------------------------------------------
// fc1 GEMM: cur1[m][co] = sum_c spk[m][c] * fc1_w[co][c], exact.
// A = spikes (0/1, one exact i8 digit); B = 5-digit fc1 planes.
// Block 32 rows x 128 cols, 8 waves, wave = 16x32 (2 subtiles), K=512 (8 kt).
// All staging via global_load_lds. Writes cur1 into the (dead) seq buffer.
// ---------------------------------------------------------------------------
__global__ __launch_bounds__(512) void fc1_gemm_kernel(
    const signed char* __restrict__ Sd, const signed char* __restrict__ Fd,
    double* __restrict__ cur1)
{
    __shared__ __align__(16) signed char AldsK[2048];      // 2 m-tiles
    __shared__ __align__(16) signed char BldsK[5 * 8192];  // 5 planes x 8 ct

    const int tid = threadIdx.x;
    const int nMB = MCHUNK / 32;           // 496
    const int bm  = blockIdx.x % nMB;
    const int bnk = blockIdx.x / nMB;
    const int m0 = bm * 32, n0 = bnk * 128;

    const int wv  = tid >> 6;
    const int l   = tid & 63;
    const int rgM = wv >> 2;
    const int cw  = wv & 3;

    v4i acc[2][5];
    #pragma unroll
    for (int s = 0; s < 2; ++s)
        #pragma unroll
        for (int d = 0; d < 5; ++d) acc[s][d] = (v4i){0, 0, 0, 0};

    for (int kt = 0; kt < 8; ++kt) {
        __syncthreads();                   // previous fragment reads complete
        #pragma unroll
        for (int i = 0; i < 5; ++i) {      // B: 40 slots = 8 waves x 5
            const int s   = wv * 5 + i;
            const int q   = s >> 3;
            const int ctl = s & 7;
            const signed char* gsrc = Fd + (size_t)q * 262144
                + (((size_t)(kt * 32 + bnk * 8 + ctl)) << 10) + l * 16;
            gl_lds16(gsrc, BldsK + q * 8192 + ctl * 1024);
        }
        if (wv < 2) {                      // A: 2 slots (m-tiles)
            const signed char* gsrc = Sd
                + (((size_t)(kt * NMT + bm * 2 + wv)) << 10) + l * 16;
            gl_lds16(gsrc, AldsK + wv * 1024);
        }
        __syncthreads();                   // staged data visible

        v4i aF = *(const v4i*)(AldsK + (rgM << 10) + (l << 4));
        #define MF(A_, B_, C_) __builtin_amdgcn_mfma_i32_16x16x64_i8(A_, B_, C_, 0, 0, 0)
        #pragma unroll
        for (int s = 0; s < 2; ++s) {
            const signed char* bb = BldsK + ((cw * 2 + s) << 10) + (l << 4);
            acc[s][0] = MF(aF, *(const v4i*)(bb),         acc[s][0]);
            acc[s][1] = MF(aF, *(const v4i*)(bb + 8192),  acc[s][1]);
            acc[s][2] = MF(aF, *(const v4i*)(bb + 16384), acc[s][2]);
            acc[s][3] = MF(aF, *(const v4i*)(bb + 24576), acc[s][3]);
            acc[s][4] = MF(aF, *(const v4i*)(bb + 32768), acc[s][4]);
        }
        #undef MF
    }

    const int l15 = l & 15;
    const int rq  = l >> 4;
    #pragma unroll
    for (int s = 0; s < 2; ++s) {
        const int co = n0 + (cw * 2 + s) * 16 + l15;
        #pragma unroll
        for (int r = 0; r < 4; ++r) {
            double v = (double)acc[s][0][r] * 0x1p-9
                     + (double)acc[s][1][r] * 0x1p-16
                     + (double)acc[s][2][r] * 0x1p-23
                     + (double)acc[s][3][r] * 0x1p-30
                     + (double)acc[s][4][r] * 0x1p-37;
            int m = m0 + rgM * 16 + rq * 4 + r;
            cur1[(size_t)m * COUT + co] = v;
        }
    }
}

// ---------------------------------------------------------------------------
// Hidden + output scan: per block one batch row; hm recurrence from cur1,
// fc2 via shfl+LDS reduce, output-neuron recurrence on threads 0/1.
// ---------------------------------------------------------------------------
__global__ __launch_bounds__(512, 4) void hid_out_scan_kernel(
    const double* __restrict__ cur1, const float* __restrict__ fc1_b,
    const float* __restrict__ fc2_w, const float* __restrict__ fc2_b,
    const float* __restrict__ beta_hid, const float* __restrict__ beta_out,
    float* __restrict__ out, int b_base)
{
    __shared__ double red[8][2];

    const int tid  = threadIdx.x;
    const int lane = tid & 63;
    const int wave = tid >> 6;
    const int row  = blockIdx.x;
    const int brow = b_base + row;

    const double bh  = clip01d((double)beta_hid[tid]);
    const double f1b = (double)fc1_b[tid];
    const double w2a = (double)fc2_w[tid];
    const double w2b = (double)fc2_w[COUT + tid];

    double bo = 0.0, f2b = 0.0, om = 0.0;
    if (tid < 2) { bo = clip01d((double)beta_out[tid]); f2b = (double)fc2_b[tid]; }

    double hm = 0.0;
    const double* cp = cur1 + (size_t)row * T_STEPS * COUT + tid;

    for (int t = 0; t < T_STEPS; ++t) {
        double cur = cp[(size_t)t * COUT] + f1b;
        double h = bh * hm + cur - ((hm > 1.0) ? 1.0 : 0.0);
        hm = h;
        double sh = (h > 1.0) ? 1.0 : 0.0;
        double p0 = sh * w2a;
        double p1 = sh * w2b;
        #pragma unroll
        for (int off = 32; off > 0; off >>= 1) {
            p0 += __shfl_down(p0, off);
            p1 += __shfl_down(p1, off);
        }
        if (lane == 0) { red[wave][0] = p0; red[wave][1] = p1; }
        __syncthreads();
        if (tid < 2) {
            double cur2 = f2b;
            #pragma unroll
            for (int w = 0; w < 8; ++w) cur2 += red[w][tid];
            double o = bo * om + cur2 - ((om > 1.0) ? 1.0 : 0.0);
            om = o;
            float so = (o > 1.0) ? 1.0f : 0.0f;
            int bidx = brow * 2 + tid;
            out[2048 + t * 2048 + bidx] = so;               // spk_rec
            out[2048 + 63488 + t * 2048 + bidx] = (float)o; // mem_rec
            if (t == T_STEPS - 1) out[bidx] = (float)o;     // final om
        }
        __syncthreads();                   // red reads done before next write
    }
}

// ---------------------------------------------------------------------------
// SNN scan v3 (fallback path only, unchanged from R12).
// ---------------------------------------------------------------------------
__global__ __launch_bounds__(512, 4) void snn_scan_v3_kernel(
    const double* __restrict__ seq, const float* __restrict__ fc1wT,
    const float* __restrict__ fc1_b, const float* __restrict__ fc2_w,
    const float* __restrict__ fc2_b, const float* __restrict__ beta_enc,
    const float* __restrict__ beta_hid, const float* __restrict__ beta_out,
    float* __restrict__ out, int b_base)
{
    __shared__ int   list[COUT];
    __shared__ int   wcnt[8];
    __shared__ double red[8][2];

    const int tid  = threadIdx.x;
    const int lane = tid & 63;
    const int wave = tid >> 6;
    const int row  = blockIdx.x;
    const int brow = b_base + row;

    const double be  = clip01d((double)beta_enc[tid]);
    const double bh  = clip01d((double)beta_hid[tid]);
    const double f1b = (double)fc1_b[tid];
    const double w2a = (double)fc2_w[tid];
    const double w2b = (double)fc2_w[COUT + tid];

    double bo = 0.0, f2b = 0.0, om = 0.0;
    if (tid < 2) { bo = clip01d((double)beta_out[tid]); f2b = (double)fc2_b[tid]; }

    double em = 0.0, hm = 0.0;
    const double* sp = seq + (size_t)row * T_STEPS * COUT + tid;

    for (int t = 0; t < T_STEPS; ++t) {
        double inp = sp[(size_t)t * COUT];
        double e = be * em + inp - ((em > 1.0) ? 1.0 : 0.0);
        em = e;
        bool spike = (e > 1.0);

        unsigned long long mask = __ballot(spike);
        if (lane == 0) wcnt[wave] = __popcll(mask);
        __syncthreads();

        int base = 0, cnt = 0;
        #pragma unroll
        for (int w = 0; w < 8; ++w) {
            int v = wcnt[w];
            base += (w < wave) ? v : 0;
            cnt  += v;
        }
        if (spike) {
            int pos = base + __popcll(mask & ((1ull << lane) - 1ull));
            list[pos] = tid;
        }
        __syncthreads();

        double s0 = 0.0, s1 = 0.0, s2 = 0.0, s3 = 0.0;
        const float* fw = fc1wT + tid;
        int i = 0;
        for (; i + 4 <= cnt; i += 4) {
            int cA = list[i], cB = list[i + 1], cC = list[i + 2], cD = list[i + 3];
            s0 += (double)fw[(size_t)cA * COUT];
            s1 += (double)fw[(size_t)cB * COUT];
            s2 += (double)fw[(size_t)cC * COUT];
            s3 += (double)fw[(size_t)cD * COUT];
        }
        for (; i < cnt; ++i) s0 += (double)fw[(size_t)list[i] * COUT];
        double cur1 = ((s0 + s1) + (s2 + s3)) + f1b;

        double h = bh * hm + cur1 - ((hm > 1.0) ? 1.0 : 0.0);
        hm = h;
        double sh = (h > 1.0) ? 1.0 : 0.0;
        double p0 = sh * w2a;
        double p1 = sh * w2b;
        #pragma unroll
        for (int off = 32; off > 0; off >>= 1) {
            p0 += __shfl_down(p0, off);
            p1 += __shfl_down(p1, off);
        }
        if (lane == 0) { red[wave][0] = p0; red[wave][1] = p1; }
        __syncthreads();

        if (tid < 2) {
            double cur2 = f2b;
            #pragma unroll
            for (int w = 0; w < 8; ++w) cur2 += red[w][tid];
            double o = bo * om + cur2 - ((om > 1.0) ? 1.0 : 0.0);
            om = o;
            float so = (o > 1.0) ? 1.0f : 0.0f;
            int bidx = brow * 2 + tid;
            out[2048 + t * 2048 + bidx] = so;
            out[2048 + 63488 + t * 2048 + bidx] = (float)o;
            if (t == T_STEPS - 1) out[bidx] = (float)o;
        }
    }
}

// ---------------------------------------------------------------------------
extern "C" void kernel_launch(void* const* d_in, const int* in_sizes, int n_in,
                              void* d_out, int out_size, void* d_ws, size_t ws_size,
                              hipStream_t stream)
{
    const float* x        = (const float*)d_in[0];
    const float* conv_w   = (const float*)d_in[1];
    const float* conv_b   = (const float*)d_in[2];
    const float* bn_gamma = (const float*)d_in[3];
    const float* bn_beta  = (const float*)d_in[4];
    const float* bn_mean  = (const float*)d_in[5];
    const float* bn_var   = (const float*)d_in[6];
    const float* fc1_w    = (const float*)d_in[7];
    const float* fc1_b    = (const float*)d_in[8];
    const float* fc2_w    = (const float*)d_in[9];
    const float* fc2_b    = (const float*)d_in[10];
    const float* beta_enc = (const float*)d_in[11];
    const float* beta_hid = (const float*)d_in[12];
    const float* beta_out = (const float*)d_in[13];
    float* out = (float*)d_out;

    // big-path ws layout: Bd@0 (5MB) | Fd@5M (1.25MB) | Sd@7M (7.75MB) |
    //                     seq/cur1@16M (62MB)  -> need 81,788,928 B
    const size_t NEED_BIG = 16ull * 1048576 + (size_t)MCHUNK * COUT * 8;
    signed char* Bd = (signed char*)d_ws;

    if (ws_size >= NEED_BIG) {
        signed char* Fd  = (signed char*)d_ws + 5 * 1048576;
        signed char* Sd  = (signed char*)d_ws + 7 * 1048576;
        double*      seq = (double*)((char*)d_ws + 16 * 1048576);  // also cur1

        prep_bd_kernel<<<1024, 256, 0, stream>>>(conv_w, Bd);
        prep_fd_kernel<<<256, 256, 0, stream>>>(fc1_w, Fd);

        for (int chunk = 0; chunk < 2; ++chunk) {
            int b_base = chunk * BCHUNK;
            conv_bn_i8v6_kernel<<<(MCHUNK / 32) * (COUT / 128), 512, 0, stream>>>(
                x, Bd, conv_b, bn_gamma, bn_beta, bn_mean, bn_var, seq, b_base);
            enc_scan_kernel<<<BCHUNK, 512, 0, stream>>>(seq, beta_enc, Sd);
            fc1_gemm_kernel<<<(MCHUNK / 32) * (COUT / 128), 512, 0, stream>>>(
                Sd, Fd, seq);
            hid_out_scan_kernel<<<BCHUNK, 512, 0, stream>>>(
                seq, fc1_b, fc2_w, fc2_b, beta_hid, beta_out, out, b_base);
        }
    } else {
        // fallback: exact R12 path (71.25 MB)
        float*  fc1wT = (float*)((char*)d_ws + 5 * 1048576);
        double* seq   = (double*)((char*)d_ws + 6 * 1048576);

        prep_bd_kernel<<<1024, 256, 0, stream>>>(conv_w, Bd);
        prep_fc1_kernel<<<1024, 256, 0, stream>>>(fc1_w, fc1wT);

        for (int chunk = 0; chunk < 2; ++chunk) {
            int b_base = chunk * BCHUNK;
            conv_bn_i8v6_kernel<<<(MCHUNK / 32) * (COUT / 128), 512, 0, stream>>>(
                x, Bd, conv_b, bn_gamma, bn_beta, bn_mean, bn_var, seq, b_base);
            snn_scan_v3_kernel<<<BCHUNK, 512, 0, stream>>>(
                seq, fc1wT, fc1_b, fc2_w, fc2_b, beta_enc, beta_hid, beta_out, out, b_base);
        }
    }
}